// Round 9
// baseline (446.568 us; speedup 1.0000x reference)
//
#include <hip/hip_runtime.h>

#define D 128
#define LSTR 132   // padded LDS row stride (floats)
#define CAP 3072   // LDS sorted-edge capacity per 32-row tile (avg ~512)

typedef __attribute__((ext_vector_type(8))) short short8;
typedef __attribute__((ext_vector_type(4))) float f32x4;

static __device__ __forceinline__ unsigned short f2bf(float f) {
    unsigned u = __float_as_uint(f);
    return (unsigned short)((u + 0x7fffu + ((u >> 16) & 1u)) >> 16);  // RNE
}
static __device__ __forceinline__ float b2f(unsigned short u) {
    return __uint_as_float(((unsigned)u) << 16);
}

// ---------------------------------------------------------------------------
// GraphSAGE (mean) x2 + head. bf16 features (fp32 accumulate).
// CSR-by-tile built with a two-phase counting sort (NO global atomics):
//   histA: per-block LDS histogram over 32-row tiles -> G[blk][bin]
//   scanB: per-bin exclusive prefix over blocks (in place) -> tot[bin]
//   scanC: single-block scan of tot -> tile_base[]
//   fillB: LDS rank replay -> csr[tile_base+G+rank] = src | dst<<16
// sage: in-LDS 32-bin counting sort of the tile's edges (row-grouped), then
// segmented register gather + MFMA dual GEMM (mean at A-frag build).
// d_ws: tot[2048] | tile_base[2049] | G[nblkA*nbins] | csr[Epad]
//       | xb bf16[N*D] | hb bf16[N*D] | Bt1 bf16[128*256] | Bt2 bf16[128*256]
// ---------------------------------------------------------------------------

__global__ void prep_kernel(const float* __restrict__ x,
                            const float* __restrict__ W1l,
                            const float* __restrict__ W1r,
                            const float* __restrict__ W2l,
                            const float* __restrict__ W2r,
                            unsigned* __restrict__ xb2,
                            unsigned short* __restrict__ Bt1,
                            unsigned short* __restrict__ Bt2, int NX2) {
    const int i = blockIdx.x * blockDim.x + threadIdx.x;
    if (i < NX2) {
        const float2 v = *(const float2*)(x + 2 * (size_t)i);
        xb2[i] = (unsigned)f2bf(v.x) | ((unsigned)f2bf(v.y) << 16);
    } else if (i < NX2 + 2 * 32768) {
        const int j = i - NX2;
        const int which = j >> 15;  // 0 -> layer1, 1 -> layer2
        const int jj = j & 32767;
        const int n = jj >> 8;
        const int k = jj & 255;
        const float* Wl = which ? W2l : W1l;
        const float* Wr = which ? W2r : W1r;
        const float w = (k < 128) ? Wl[k * 128 + n] : Wr[(k - 128) * 128 + n];
        (which ? Bt2 : Bt1)[jj] = f2bf(w);
    }
}

// Phase A: per-block (1024 edges) LDS histogram over tiles.
__global__ __launch_bounds__(256) void histA_kernel(const int* __restrict__ dst,
                                                    int E, int nbins,
                                                    unsigned* __restrict__ G) {
    __shared__ int h[2048];
    const int t = threadIdx.x;
    for (int i = t; i < nbins; i += 256) h[i] = 0;
    __syncthreads();
    const int base = blockIdx.x * 1024;
    for (int i = t; i < 1024; i += 256) {
        const int e = base + i;
        if (e < E) atomicAdd(&h[dst[e] >> 5], 1);
    }
    __syncthreads();
    unsigned* g = G + (size_t)blockIdx.x * nbins;
    for (int i = t; i < nbins; i += 256) g[i] = (unsigned)h[i];
}

// Per-bin exclusive prefix over blocks, in place; tot[bin] = column total.
__global__ void scanB_kernel(unsigned* __restrict__ G, int nblkA, int nbins,
                             int* __restrict__ tot) {
    const int bin = blockIdx.x * 256 + threadIdx.x;
    if (bin >= nbins) return;
    unsigned run = 0;
    for (int b = 0; b < nblkA; ++b) {
        unsigned* p = G + (size_t)b * nbins + bin;
        const unsigned v = *p;
        *p = run;
        run += v;
    }
    tot[bin] = (int)run;
}

// Single-block exclusive scan of tot -> tile_base[0..nbins].
__global__ __launch_bounds__(1024) void scanC_kernel(
    const int* __restrict__ tot, int nbins, int* __restrict__ tile_base) {
    __shared__ int part[1024];
    const int t = threadIdx.x;
    const int chunk = (nbins + 1023) >> 10;
    const int lo = min(t * chunk, nbins);
    const int hi = min(lo + chunk, nbins);
    int s = 0;
    for (int i = lo; i < hi; ++i) s += tot[i];
    part[t] = s;
    __syncthreads();
    for (int off = 1; off < 1024; off <<= 1) {
        int add = (t >= off) ? part[t - off] : 0;
        __syncthreads();
        part[t] += add;
        __syncthreads();
    }
    int excl = (t == 0) ? 0 : part[t - 1];
    for (int i = lo; i < hi; ++i) {
        tile_base[i] = excl;
        excl += tot[i];
    }
    if (t == 1023) tile_base[nbins] = part[1023];
}

// Phase B: rank replay + scatter into tile-grouped csr.
__global__ __launch_bounds__(256) void fillB_kernel(
    const int* __restrict__ src, const int* __restrict__ dst, int E,
    const unsigned* __restrict__ G, const int* __restrict__ tile_base,
    unsigned* __restrict__ csr, int nbins) {
    __shared__ int rank[2048];
    const int t = threadIdx.x;
    for (int i = t; i < nbins; i += 256) rank[i] = 0;
    __syncthreads();
    const int base = blockIdx.x * 1024;
    const unsigned* g = G + (size_t)blockIdx.x * nbins;
    for (int i = t; i < 1024; i += 256) {
        const int e = base + i;
        if (e < E) {
            const int d = dst[e];
            const int bin = d >> 5;
            const int r = atomicAdd(&rank[bin], 1);
            const int pos = tile_base[bin] + (int)g[bin] + r;
            csr[pos] = (unsigned)src[e] | ((unsigned)d << 16);
        }
    }
}

// Fused: in-LDS row sort -> segmented bf16 gather (fp32 acc) -> MFMA dual
// GEMM with mean applied at A-frag build. HEAD folds the Linear(128,1).
template <bool HEAD>
__global__ __launch_bounds__(256) void sage_kernel(
    const unsigned short* __restrict__ xb, const unsigned* __restrict__ csr,
    const int* __restrict__ tile_base,
    const unsigned short* __restrict__ Bt,  // [128 n][256 k] bf16
    const float* __restrict__ bl, const float* __restrict__ Wout,
    const float* __restrict__ bout, unsigned short* __restrict__ hb_out,
    float* __restrict__ out, int N) {
    __shared__ float aggL[32 * LSTR];
    __shared__ unsigned sortedE[CAP];
    __shared__ int rowcnt[32];
    __shared__ int rowofs[32];
    __shared__ float invL[32];
    __shared__ float redH[64];

    const int b = blockIdx.x;
    const int i0 = b * 32;
    const int t = threadIdx.x;
    const int g = t >> 5;
    const int l = t & 31;
    const int c4 = l << 2;

    const int rs0 = tile_base[b];
    const int re0 = tile_base[b + 1];
    const int nE = re0 - rs0;
    const bool use_sorted = (nE <= CAP);

    for (int i = t; i < 32 * LSTR; i += 256) aggL[i] = 0.f;
    if (t < 32) rowcnt[t] = 0;
    __syncthreads();

    // count per-row degree (also feeds invL)
    for (int i = t; i < nE; i += 256)
        atomicAdd(&rowcnt[(csr[rs0 + i] >> 16) & 31], 1);
    __syncthreads();

    if (t < 32) {
        const int v = rowcnt[t];
        invL[t] = 1.0f / fmaxf((float)v, 1.0f);
        int s = v;
#pragma unroll
        for (int off = 1; off < 32; off <<= 1) {
            const int u = __shfl_up(s, off, 32);
            if (l >= off) s += u;
        }
        rowofs[t] = s - v;  // exclusive prefix, reused as scatter cursor
    }
    __syncthreads();

    if (use_sorted) {
        for (int i = t; i < nE; i += 256) {
            const unsigned p = csr[rs0 + i];
            const int k = atomicAdd(&rowofs[(p >> 16) & 31], 1);
            sortedE[k] = p;
        }
    }
    __syncthreads();

    // ---- segmented edge-parallel aggregation ----
    int e = (nE * g) >> 3;
    const int ee = (nE * (g + 1)) >> 3;

    auto getp = [&](int idx) -> unsigned {
        return use_sorted ? sortedE[idx] : csr[rs0 + idx];
    };

    float4 acc = make_float4(0.f, 0.f, 0.f, 0.f);
    int cur = (e < ee) ? (int)(getp(e) >> 16) - i0 : -1;

    auto load4 = [&](unsigned p) -> float4 {
        const ushort4 u =
            *(const ushort4*)(xb + (size_t)(p & 0xffffu) * D + c4);
        float4 v;
        v.x = b2f(u.x); v.y = b2f(u.y); v.z = b2f(u.z); v.w = b2f(u.w);
        return v;
    };
    auto step = [&](unsigned p, const float4& v) {
        const int r = (int)(p >> 16) - i0;
        if (r != cur) {
            float* q = aggL + cur * LSTR + c4;
            atomicAdd(q + 0, acc.x);
            atomicAdd(q + 1, acc.y);
            atomicAdd(q + 2, acc.z);
            atomicAdd(q + 3, acc.w);
            acc = make_float4(0.f, 0.f, 0.f, 0.f);
            cur = r;
        }
        acc.x += v.x; acc.y += v.y; acc.z += v.z; acc.w += v.w;
    };

    while (e + 8 <= ee) {
        const unsigned p0 = getp(e + 0), p1 = getp(e + 1);
        const unsigned p2 = getp(e + 2), p3 = getp(e + 3);
        const unsigned p4 = getp(e + 4), p5 = getp(e + 5);
        const unsigned p6 = getp(e + 6), p7 = getp(e + 7);
        const float4 v0 = load4(p0), v1 = load4(p1), v2 = load4(p2),
                     v3 = load4(p3), v4 = load4(p4), v5 = load4(p5),
                     v6 = load4(p6), v7 = load4(p7);
        step(p0, v0); step(p1, v1); step(p2, v2); step(p3, v3);
        step(p4, v4); step(p5, v5); step(p6, v6); step(p7, v7);
        e += 8;
    }
    while (e < ee) {
        const unsigned p = getp(e);
        step(p, load4(p));
        ++e;
    }
    if (cur >= 0) {
        float* q = aggL + cur * LSTR + c4;
        atomicAdd(q + 0, acc.x);
        atomicAdd(q + 1, acc.y);
        atomicAdd(q + 2, acc.z);
        atomicAdd(q + 3, acc.w);
    }
    __syncthreads();

    // ---- MFMA dual GEMM: [agg*inv | x](32x256) @ Bt^T(256x128) ----
    const int wave = t >> 6;
    const int lane = t & 63;
    const int ln = lane & 15;
    const int quad = lane >> 4;
    const int mtile = wave & 1;       // rows mtile*16..+15
    const int nt0 = (wave >> 1) * 4;  // 4 n-tiles per wave
    const int mrow = mtile * 16 + ln;
    const int gmr = i0 + mrow;
    const float inv = invL[mrow];

    f32x4 acc4[4] = {f32x4{0.f, 0.f, 0.f, 0.f}, f32x4{0.f, 0.f, 0.f, 0.f},
                     f32x4{0.f, 0.f, 0.f, 0.f}, f32x4{0.f, 0.f, 0.f, 0.f}};

#pragma unroll
    for (int s = 0; s < 4; ++s) {
        const int kb = s * 32 + quad * 8;
        const float* ap = aggL + mrow * LSTR + kb;
        const float4 fa = *(const float4*)ap;
        const float4 fb = *(const float4*)(ap + 4);
        const short8 aA = {(short)f2bf(fa.x * inv), (short)f2bf(fa.y * inv),
                           (short)f2bf(fa.z * inv), (short)f2bf(fa.w * inv),
                           (short)f2bf(fb.x * inv), (short)f2bf(fb.y * inv),
                           (short)f2bf(fb.z * inv), (short)f2bf(fb.w * inv)};
        short8 aX = {0, 0, 0, 0, 0, 0, 0, 0};
        if (gmr < N) aX = *(const short8*)(xb + (size_t)gmr * D + kb);
#pragma unroll
        for (int nt = 0; nt < 4; ++nt) {
            const int n = (nt0 + nt) * 16 + ln;
            const short8 b1 = *(const short8*)(Bt + n * 256 + kb);
            const short8 b2 = *(const short8*)(Bt + n * 256 + 128 + kb);
            acc4[nt] = __builtin_amdgcn_mfma_f32_16x16x32_bf16(aA, b1, acc4[nt],
                                                               0, 0, 0);
            acc4[nt] = __builtin_amdgcn_mfma_f32_16x16x32_bf16(aX, b2, acc4[nt],
                                                               0, 0, 0);
        }
    }

    // ---- epilogue: C/D layout col=lane&15, row=quad*4+reg ----
    float biasv[4], woutv[4];
#pragma unroll
    for (int nt = 0; nt < 4; ++nt) {
        const int col = (nt0 + nt) * 16 + ln;
        biasv[nt] = bl[col];
        if (HEAD) woutv[nt] = Wout[col];
    }

    if (!HEAD) {
#pragma unroll
        for (int r = 0; r < 4; ++r) {
            const int gr = i0 + mtile * 16 + quad * 4 + r;
            if (gr < N) {
#pragma unroll
                for (int nt = 0; nt < 4; ++nt) {
                    const int col = (nt0 + nt) * 16 + ln;
                    const float v = fmaxf(acc4[nt][r] + biasv[nt], 0.f);
                    hb_out[(size_t)gr * D + col] = f2bf(v);
                }
            }
        }
    } else {
        const float b0 = bout[0];
#pragma unroll
        for (int r = 0; r < 4; ++r) {
            const int row = mtile * 16 + quad * 4 + r;
            float p = 0.f;
#pragma unroll
            for (int nt = 0; nt < 4; ++nt) {
                const float v = fmaxf(acc4[nt][r] + biasv[nt], 0.f);
                p += v * woutv[nt];
            }
            p += __shfl_xor(p, 1);
            p += __shfl_xor(p, 2);
            p += __shfl_xor(p, 4);
            p += __shfl_xor(p, 8);
            if (ln == 0) redH[row * 2 + (wave >> 1)] = p;
        }
        __syncthreads();
        if (t < 32) {
            const int gr = i0 + t;
            if (gr < N) out[gr] = redH[t * 2] + redH[t * 2 + 1] + b0;
        }
    }
}

extern "C" void kernel_launch(void* const* d_in, const int* in_sizes, int n_in,
                              void* d_out, int out_size, void* d_ws,
                              size_t ws_size, hipStream_t stream) {
    const float* x = (const float*)d_in[0];
    const int* ei = (const int*)d_in[1];
    const float* W1l = (const float*)d_in[2];
    const float* b1l = (const float*)d_in[3];
    const float* W1r = (const float*)d_in[4];
    const float* W2l = (const float*)d_in[5];
    const float* b2l = (const float*)d_in[6];
    const float* W2r = (const float*)d_in[7];
    const float* Wout = (const float*)d_in[8];
    const float* bout = (const float*)d_in[9];

    const int N = in_sizes[0] / D;
    const int E = in_sizes[1] / 2;
    const int* src = ei;
    const int* dst = ei + E;

    const int nbins = (N + 31) / 32;        // 32-row tiles (= sage blocks)
    const int nblkA = (E + 1023) / 1024;    // edge chunks
    const size_t Epad = (size_t)((E + 255) & ~255);

    int* tot = (int*)d_ws;                       // [2048]
    int* tile_base = tot + 2048;                 // [2049]
    unsigned* G = (unsigned*)(tile_base + 2049 + 3);  // [nblkA*nbins]
    unsigned* csr = G + (size_t)nblkA * nbins;
    unsigned short* xb = (unsigned short*)(csr + Epad);
    unsigned short* hb = xb + (size_t)N * D;
    unsigned short* Bt1 = hb + (size_t)N * D;
    unsigned short* Bt2 = Bt1 + 128 * 256;
    float* out = (float*)d_out;

    const int NX2 = N * D / 2;
    const int prep_total = NX2 + 2 * 32768;

    prep_kernel<<<(prep_total + 255) / 256, 256, 0, stream>>>(
        x, W1l, W1r, W2l, W2r, (unsigned*)xb, Bt1, Bt2, NX2);
    histA_kernel<<<nblkA, 256, 0, stream>>>(dst, E, nbins, G);
    scanB_kernel<<<(nbins + 255) / 256, 256, 0, stream>>>(G, nblkA, nbins, tot);
    scanC_kernel<<<1, 1024, 0, stream>>>(tot, nbins, tile_base);
    fillB_kernel<<<nblkA, 256, 0, stream>>>(src, dst, E, G, tile_base, csr,
                                            nbins);

    sage_kernel<false><<<nbins, 256, 0, stream>>>(
        xb, csr, tile_base, Bt1, b1l, nullptr, nullptr, hb, nullptr, N);
    sage_kernel<true><<<nbins, 256, 0, stream>>>(
        hb, csr, tile_base, Bt2, b2l, Wout, bout, nullptr, out, N);
}

// Round 10
// 269.204 us; speedup vs baseline: 1.6588x; 1.6588x over previous
//
#include <hip/hip_runtime.h>

#define D 128
#define LSTR 132   // padded LDS row stride (floats)
#define CAP 3072   // LDS sorted-edge capacity per 32-row tile (avg ~512)
#define NBLK 256   // fixed hist/fill block count (G columns)

typedef __attribute__((ext_vector_type(8))) short short8;
typedef __attribute__((ext_vector_type(4))) float f32x4;

static __device__ __forceinline__ unsigned short f2bf(float f) {
    unsigned u = __float_as_uint(f);
    return (unsigned short)((u + 0x7fffu + ((u >> 16) & 1u)) >> 16);  // RNE
}
static __device__ __forceinline__ float b2f(unsigned short u) {
    return __uint_as_float(((unsigned)u) << 16);
}

// ---------------------------------------------------------------------------
// GraphSAGE (mean) x2 + head. bf16 features (fp32 accumulate).
// CSR-by-tile via two-phase counting sort, NO global atomics:
//   histA: 256 blocks, LDS histogram over 32-row tiles -> G[bin][blk]
//   scanB: one WAVE per bin, coalesced uint4 scan over the 256 blocks
//   scanC: single-block scan of bin totals -> tile_base[]
//   fillB: LDS rank replay -> csr[tile_base+G+rank] = src | dst<<16
// sage: in-LDS 32-bin counting sort of the tile's edges, segmented register
// gather + MFMA dual GEMM (mean at A-frag build). HEAD folds Linear(128,1).
// d_ws: tot[2048] | tile_base[2052] | G[2048*256] | csr[Epad]
//       | xb bf16[N*D] | hb bf16[N*D] | Bt1 bf16[128*256] | Bt2 bf16[128*256]
// ---------------------------------------------------------------------------

__global__ void prep_kernel(const float* __restrict__ x,
                            const float* __restrict__ W1l,
                            const float* __restrict__ W1r,
                            const float* __restrict__ W2l,
                            const float* __restrict__ W2r,
                            unsigned* __restrict__ xb2,
                            unsigned short* __restrict__ Bt1,
                            unsigned short* __restrict__ Bt2, int NX2) {
    const int i = blockIdx.x * blockDim.x + threadIdx.x;
    if (i < NX2) {
        const float2 v = *(const float2*)(x + 2 * (size_t)i);
        xb2[i] = (unsigned)f2bf(v.x) | ((unsigned)f2bf(v.y) << 16);
    } else if (i < NX2 + 2 * 32768) {
        const int j = i - NX2;
        const int which = j >> 15;  // 0 -> layer1, 1 -> layer2
        const int jj = j & 32767;
        const int n = jj >> 8;
        const int k = jj & 255;
        const float* Wl = which ? W2l : W1l;
        const float* Wr = which ? W2r : W1r;
        const float w = (k < 128) ? Wl[k * 128 + n] : Wr[(k - 128) * 128 + n];
        (which ? Bt2 : Bt1)[jj] = f2bf(w);
    }
}

// Phase A: 256 blocks, each histograms its contiguous edge slice into LDS,
// then writes its column G[bin][blk].
__global__ __launch_bounds__(256) void histA_kernel(const int* __restrict__ dst,
                                                    int E, int nbins,
                                                    unsigned* __restrict__ G) {
    __shared__ int h[2048];
    const int t = threadIdx.x;
    for (int i = t; i < nbins; i += 256) h[i] = 0;
    __syncthreads();
    const int per = (E + NBLK - 1) / NBLK;
    const int lo = blockIdx.x * per;
    const int hi = min(lo + per, E);
    for (int i = lo + t; i < hi; i += 256) atomicAdd(&h[dst[i] >> 5], 1);
    __syncthreads();
    for (int i = t; i < nbins; i += 256)
        G[(size_t)i * NBLK + blockIdx.x] = (unsigned)h[i];
}

// One wave per bin: coalesced uint4 exclusive scan over the 256 columns.
__global__ __launch_bounds__(256) void scanB_kernel(unsigned* __restrict__ G,
                                                    int nbins,
                                                    int* __restrict__ tot) {
    const int wave = threadIdx.x >> 6;
    const int lane = threadIdx.x & 63;
    const int bin = blockIdx.x * 4 + wave;
    if (bin >= nbins) return;
    unsigned* p = G + (size_t)bin * NBLK + lane * 4;
    uint4 v = *(uint4*)p;
    const unsigned s = v.x + v.y + v.z + v.w;
    unsigned sc = s;
#pragma unroll
    for (int off = 1; off < 64; off <<= 1) {
        const unsigned u = (unsigned)__shfl_up((int)sc, off, 64);
        if (lane >= off) sc += u;
    }
    const unsigned excl = sc - s;
    uint4 w;
    w.x = excl;
    w.y = excl + v.x;
    w.z = excl + v.x + v.y;
    w.w = excl + v.x + v.y + v.z;
    *(uint4*)p = w;
    if (lane == 63) tot[bin] = (int)(excl + s);
}

// Single-block exclusive scan of tot -> tile_base[0..nbins].
__global__ __launch_bounds__(1024) void scanC_kernel(
    const int* __restrict__ tot, int nbins, int* __restrict__ tile_base) {
    __shared__ int part[1024];
    const int t = threadIdx.x;
    const int chunk = (nbins + 1023) >> 10;
    const int lo = min(t * chunk, nbins);
    const int hi = min(lo + chunk, nbins);
    int s = 0;
    for (int i = lo; i < hi; ++i) s += tot[i];
    part[t] = s;
    __syncthreads();
    for (int off = 1; off < 1024; off <<= 1) {
        int add = (t >= off) ? part[t - off] : 0;
        __syncthreads();
        part[t] += add;
        __syncthreads();
    }
    int excl = (t == 0) ? 0 : part[t - 1];
    for (int i = lo; i < hi; ++i) {
        tile_base[i] = excl;
        excl += tot[i];
    }
    if (t == 1023) tile_base[nbins] = part[1023];
}

// Phase B: rank replay + scatter into tile-grouped csr.
__global__ __launch_bounds__(256) void fillB_kernel(
    const int* __restrict__ src, const int* __restrict__ dst, int E,
    const unsigned* __restrict__ G, const int* __restrict__ tile_base,
    unsigned* __restrict__ csr, int nbins) {
    __shared__ int rank[2048];
    __shared__ int base[2048];
    const int t = threadIdx.x;
    for (int i = t; i < nbins; i += 256) {
        rank[i] = 0;
        base[i] = tile_base[i] + (int)G[(size_t)i * NBLK + blockIdx.x];
    }
    __syncthreads();
    const int per = (E + NBLK - 1) / NBLK;
    const int lo = blockIdx.x * per;
    const int hi = min(lo + per, E);
    for (int i = lo + t; i < hi; i += 256) {
        const int d = dst[i];
        const int bin = d >> 5;
        const int r = atomicAdd(&rank[bin], 1);
        csr[base[bin] + r] = (unsigned)src[i] | ((unsigned)d << 16);
    }
}

// Fused: in-LDS row sort -> segmented bf16 gather (fp32 acc) -> MFMA dual
// GEMM with mean applied at A-frag build. HEAD folds the Linear(128,1).
template <bool HEAD>
__global__ __launch_bounds__(256) void sage_kernel(
    const unsigned short* __restrict__ xb, const unsigned* __restrict__ csr,
    const int* __restrict__ tile_base,
    const unsigned short* __restrict__ Bt,  // [128 n][256 k] bf16
    const float* __restrict__ bl, const float* __restrict__ Wout,
    const float* __restrict__ bout, unsigned short* __restrict__ hb_out,
    float* __restrict__ out, int N) {
    __shared__ float aggL[32 * LSTR];
    __shared__ unsigned sortedE[CAP];
    __shared__ int rowcnt[32];
    __shared__ int rowofs[32];
    __shared__ float invL[32];
    __shared__ float redH[64];

    const int b = blockIdx.x;
    const int i0 = b * 32;
    const int t = threadIdx.x;
    const int g = t >> 5;
    const int l = t & 31;
    const int c4 = l << 2;

    const int rs0 = tile_base[b];
    const int re0 = tile_base[b + 1];
    const int nE = re0 - rs0;
    const bool use_sorted = (nE <= CAP);

    for (int i = t; i < 32 * LSTR; i += 256) aggL[i] = 0.f;
    if (t < 32) rowcnt[t] = 0;
    __syncthreads();

    // count per-row degree (also feeds invL)
    for (int i = t; i < nE; i += 256)
        atomicAdd(&rowcnt[(csr[rs0 + i] >> 16) & 31], 1);
    __syncthreads();

    if (t < 32) {
        const int v = rowcnt[t];
        invL[t] = 1.0f / fmaxf((float)v, 1.0f);
        int s = v;
#pragma unroll
        for (int off = 1; off < 32; off <<= 1) {
            const int u = __shfl_up(s, off, 32);
            if (l >= off) s += u;
        }
        rowofs[t] = s - v;  // exclusive prefix, reused as scatter cursor
    }
    __syncthreads();

    if (use_sorted) {
        for (int i = t; i < nE; i += 256) {
            const unsigned p = csr[rs0 + i];
            const int k = atomicAdd(&rowofs[(p >> 16) & 31], 1);
            sortedE[k] = p;
        }
    }
    __syncthreads();

    // ---- segmented edge-parallel aggregation ----
    int e = (nE * g) >> 3;
    const int ee = (nE * (g + 1)) >> 3;

    auto getp = [&](int idx) -> unsigned {
        return use_sorted ? sortedE[idx] : csr[rs0 + idx];
    };

    float4 acc = make_float4(0.f, 0.f, 0.f, 0.f);
    int cur = (e < ee) ? (int)(getp(e) >> 16) - i0 : -1;

    auto load4 = [&](unsigned p) -> float4 {
        const ushort4 u =
            *(const ushort4*)(xb + (size_t)(p & 0xffffu) * D + c4);
        float4 v;
        v.x = b2f(u.x); v.y = b2f(u.y); v.z = b2f(u.z); v.w = b2f(u.w);
        return v;
    };
    auto step = [&](unsigned p, const float4& v) {
        const int r = (int)(p >> 16) - i0;
        if (r != cur) {
            float* q = aggL + cur * LSTR + c4;
            atomicAdd(q + 0, acc.x);
            atomicAdd(q + 1, acc.y);
            atomicAdd(q + 2, acc.z);
            atomicAdd(q + 3, acc.w);
            acc = make_float4(0.f, 0.f, 0.f, 0.f);
            cur = r;
        }
        acc.x += v.x; acc.y += v.y; acc.z += v.z; acc.w += v.w;
    };

    while (e + 8 <= ee) {
        const unsigned p0 = getp(e + 0), p1 = getp(e + 1);
        const unsigned p2 = getp(e + 2), p3 = getp(e + 3);
        const unsigned p4 = getp(e + 4), p5 = getp(e + 5);
        const unsigned p6 = getp(e + 6), p7 = getp(e + 7);
        const float4 v0 = load4(p0), v1 = load4(p1), v2 = load4(p2),
                     v3 = load4(p3), v4 = load4(p4), v5 = load4(p5),
                     v6 = load4(p6), v7 = load4(p7);
        step(p0, v0); step(p1, v1); step(p2, v2); step(p3, v3);
        step(p4, v4); step(p5, v5); step(p6, v6); step(p7, v7);
        e += 8;
    }
    while (e < ee) {
        const unsigned p = getp(e);
        step(p, load4(p));
        ++e;
    }
    if (cur >= 0) {
        float* q = aggL + cur * LSTR + c4;
        atomicAdd(q + 0, acc.x);
        atomicAdd(q + 1, acc.y);
        atomicAdd(q + 2, acc.z);
        atomicAdd(q + 3, acc.w);
    }
    __syncthreads();

    // ---- MFMA dual GEMM: [agg*inv | x](32x256) @ Bt^T(256x128) ----
    const int wave = t >> 6;
    const int lane = t & 63;
    const int ln = lane & 15;
    const int quad = lane >> 4;
    const int mtile = wave & 1;       // rows mtile*16..+15
    const int nt0 = (wave >> 1) * 4;  // 4 n-tiles per wave
    const int mrow = mtile * 16 + ln;
    const int gmr = i0 + mrow;
    const float inv = invL[mrow];

    f32x4 acc4[4] = {f32x4{0.f, 0.f, 0.f, 0.f}, f32x4{0.f, 0.f, 0.f, 0.f},
                     f32x4{0.f, 0.f, 0.f, 0.f}, f32x4{0.f, 0.f, 0.f, 0.f}};

#pragma unroll
    for (int s = 0; s < 4; ++s) {
        const int kb = s * 32 + quad * 8;
        const float* ap = aggL + mrow * LSTR + kb;
        const float4 fa = *(const float4*)ap;
        const float4 fb = *(const float4*)(ap + 4);
        const short8 aA = {(short)f2bf(fa.x * inv), (short)f2bf(fa.y * inv),
                           (short)f2bf(fa.z * inv), (short)f2bf(fa.w * inv),
                           (short)f2bf(fb.x * inv), (short)f2bf(fb.y * inv),
                           (short)f2bf(fb.z * inv), (short)f2bf(fb.w * inv)};
        short8 aX = {0, 0, 0, 0, 0, 0, 0, 0};
        if (gmr < N) aX = *(const short8*)(xb + (size_t)gmr * D + kb);
#pragma unroll
        for (int nt = 0; nt < 4; ++nt) {
            const int n = (nt0 + nt) * 16 + ln;
            const short8 b1 = *(const short8*)(Bt + n * 256 + kb);
            const short8 b2 = *(const short8*)(Bt + n * 256 + 128 + kb);
            acc4[nt] = __builtin_amdgcn_mfma_f32_16x16x32_bf16(aA, b1, acc4[nt],
                                                               0, 0, 0);
            acc4[nt] = __builtin_amdgcn_mfma_f32_16x16x32_bf16(aX, b2, acc4[nt],
                                                               0, 0, 0);
        }
    }

    // ---- epilogue: C/D layout col=lane&15, row=quad*4+reg ----
    float biasv[4], woutv[4];
#pragma unroll
    for (int nt = 0; nt < 4; ++nt) {
        const int col = (nt0 + nt) * 16 + ln;
        biasv[nt] = bl[col];
        if (HEAD) woutv[nt] = Wout[col];
    }

    if (!HEAD) {
#pragma unroll
        for (int r = 0; r < 4; ++r) {
            const int gr = i0 + mtile * 16 + quad * 4 + r;
            if (gr < N) {
#pragma unroll
                for (int nt = 0; nt < 4; ++nt) {
                    const int col = (nt0 + nt) * 16 + ln;
                    const float v = fmaxf(acc4[nt][r] + biasv[nt], 0.f);
                    hb_out[(size_t)gr * D + col] = f2bf(v);
                }
            }
        }
    } else {
        const float b0 = bout[0];
#pragma unroll
        for (int r = 0; r < 4; ++r) {
            const int row = mtile * 16 + quad * 4 + r;
            float p = 0.f;
#pragma unroll
            for (int nt = 0; nt < 4; ++nt) {
                const float v = fmaxf(acc4[nt][r] + biasv[nt], 0.f);
                p += v * woutv[nt];
            }
            p += __shfl_xor(p, 1);
            p += __shfl_xor(p, 2);
            p += __shfl_xor(p, 4);
            p += __shfl_xor(p, 8);
            if (ln == 0) redH[row * 2 + (wave >> 1)] = p;
        }
        __syncthreads();
        if (t < 32) {
            const int gr = i0 + t;
            if (gr < N) out[gr] = redH[t * 2] + redH[t * 2 + 1] + b0;
        }
    }
}

extern "C" void kernel_launch(void* const* d_in, const int* in_sizes, int n_in,
                              void* d_out, int out_size, void* d_ws,
                              size_t ws_size, hipStream_t stream) {
    const float* x = (const float*)d_in[0];
    const int* ei = (const int*)d_in[1];
    const float* W1l = (const float*)d_in[2];
    const float* b1l = (const float*)d_in[3];
    const float* W1r = (const float*)d_in[4];
    const float* W2l = (const float*)d_in[5];
    const float* b2l = (const float*)d_in[6];
    const float* W2r = (const float*)d_in[7];
    const float* Wout = (const float*)d_in[8];
    const float* bout = (const float*)d_in[9];

    const int N = in_sizes[0] / D;
    const int E = in_sizes[1] / 2;
    const int* src = ei;
    const int* dst = ei + E;

    const int nbins = (N + 31) / 32;  // 32-row tiles (= sage blocks), <= 2048
    const size_t Epad = (size_t)((E + 255) & ~255);

    int* tot = (int*)d_ws;                        // [2048]
    int* tile_base = tot + 2048;                  // [2052]
    unsigned* G = (unsigned*)(tile_base + 2052);  // [2048 * NBLK]
    unsigned* csr = G + (size_t)2048 * NBLK;
    unsigned short* xb = (unsigned short*)(csr + Epad);
    unsigned short* hb = xb + (size_t)N * D;
    unsigned short* Bt1 = hb + (size_t)N * D;
    unsigned short* Bt2 = Bt1 + 128 * 256;
    float* out = (float*)d_out;

    const int NX2 = N * D / 2;
    const int prep_total = NX2 + 2 * 32768;

    prep_kernel<<<(prep_total + 255) / 256, 256, 0, stream>>>(
        x, W1l, W1r, W2l, W2r, (unsigned*)xb, Bt1, Bt2, NX2);
    histA_kernel<<<NBLK, 256, 0, stream>>>(dst, E, nbins, G);
    scanB_kernel<<<(nbins + 3) / 4, 256, 0, stream>>>(G, nbins, tot);
    scanC_kernel<<<1, 1024, 0, stream>>>(tot, nbins, tile_base);
    fillB_kernel<<<NBLK, 256, 0, stream>>>(src, dst, E, G, tile_base, csr,
                                           nbins);

    sage_kernel<false><<<nbins, 256, 0, stream>>>(
        xb, csr, tile_base, Bt1, b1l, nullptr, nullptr, hb, nullptr, N);
    sage_kernel<true><<<nbins, 256, 0, stream>>>(
        hb, csr, tile_base, Bt2, b2l, Wout, bout, nullptr, out, N);
}

// Round 11
// 258.379 us; speedup vs baseline: 1.7283x; 1.0419x over previous
//
#include <hip/hip_runtime.h>

#define D 128
#define LSTR 132   // padded LDS row stride (floats)
#define CAP 3072   // LDS edge capacity per 32-row tile (avg ~512)
#define NBLK 256   // fixed hist/fill block count (G columns)

typedef __attribute__((ext_vector_type(8))) short short8;
typedef __attribute__((ext_vector_type(4))) float f32x4;

static __device__ __forceinline__ unsigned short f2bf(float f) {
    unsigned u = __float_as_uint(f);
    return (unsigned short)((u + 0x7fffu + ((u >> 16) & 1u)) >> 16);  // RNE
}
static __device__ __forceinline__ float b2f(unsigned short u) {
    return __uint_as_float(((unsigned)u) << 16);
}

// ---------------------------------------------------------------------------
// GraphSAGE (mean) x2 + head. bf16 features (fp32 accumulate).
// CSR-by-tile via two-phase counting sort (no global atomics):
//   prep+histA (merged): cast x->bf16, transpose weights; LDS histogram
//     over 32-row tiles -> G[bin][blk]
//   scanB: one wave per bin, coalesced uint4 scan over 256 columns
//   scanC: single-block scan of bin totals -> tile_base[]
//   fillB: LDS rank replay -> csr[...] = src | dst<<16 (tile-grouped)
//   sortT: one block per tile, in-LDS 32-bin counting sort -> row-sorted csr
//          (in place) + invL_g[N] = 1/max(deg,1)   [runs ONCE, reused 2x]
// sage: segmented register gather over row-sorted csr + MFMA dual GEMM
//       (mean at A-frag build). HEAD folds the Linear(128,1).
// d_ws: tot[2048] | tile_base[2052] | invL_g[Npad] | G[2048*NBLK] | csr[Epad]
//       | xb bf16[N*D] | hb bf16[N*D] | Bt1 bf16[128*256] | Bt2 bf16[128*256]
// ---------------------------------------------------------------------------

// Blocks [0, NBLK): LDS histogram of dst tiles. Blocks [NBLK, ...): prep.
__global__ __launch_bounds__(256) void prep_hist_kernel(
    const float* __restrict__ x, const float* __restrict__ W1l,
    const float* __restrict__ W1r, const float* __restrict__ W2l,
    const float* __restrict__ W2r, unsigned* __restrict__ xb2,
    unsigned short* __restrict__ Bt1, unsigned short* __restrict__ Bt2,
    int NX2, const int* __restrict__ dst, int E, int nbins,
    unsigned* __restrict__ G) {
    const int t = threadIdx.x;
    if (blockIdx.x < NBLK) {
        __shared__ int h[2048];
        for (int i = t; i < nbins; i += 256) h[i] = 0;
        __syncthreads();
        const int per = (E + NBLK - 1) / NBLK;
        const int lo = blockIdx.x * per;
        const int hi = min(lo + per, E);
        for (int i = lo + t; i < hi; i += 256) atomicAdd(&h[dst[i] >> 5], 1);
        __syncthreads();
        for (int i = t; i < nbins; i += 256)
            G[(size_t)i * NBLK + blockIdx.x] = (unsigned)h[i];
        return;
    }
    const int i = (blockIdx.x - NBLK) * 256 + t;
    if (i < NX2) {
        const float2 v = *(const float2*)(x + 2 * (size_t)i);
        xb2[i] = (unsigned)f2bf(v.x) | ((unsigned)f2bf(v.y) << 16);
    } else if (i < NX2 + 2 * 32768) {
        const int j = i - NX2;
        const int which = j >> 15;  // 0 -> layer1, 1 -> layer2
        const int jj = j & 32767;
        const int n = jj >> 8;
        const int k = jj & 255;
        const float* Wl = which ? W2l : W1l;
        const float* Wr = which ? W2r : W1r;
        const float w = (k < 128) ? Wl[k * 128 + n] : Wr[(k - 128) * 128 + n];
        (which ? Bt2 : Bt1)[jj] = f2bf(w);
    }
}

// One wave per bin: coalesced uint4 exclusive scan over the 256 columns.
__global__ __launch_bounds__(256) void scanB_kernel(unsigned* __restrict__ G,
                                                    int nbins,
                                                    int* __restrict__ tot) {
    const int wave = threadIdx.x >> 6;
    const int lane = threadIdx.x & 63;
    const int bin = blockIdx.x * 4 + wave;
    if (bin >= nbins) return;
    unsigned* p = G + (size_t)bin * NBLK + lane * 4;
    uint4 v = *(uint4*)p;
    const unsigned s = v.x + v.y + v.z + v.w;
    unsigned sc = s;
#pragma unroll
    for (int off = 1; off < 64; off <<= 1) {
        const unsigned u = (unsigned)__shfl_up((int)sc, off, 64);
        if (lane >= off) sc += u;
    }
    const unsigned excl = sc - s;
    uint4 w;
    w.x = excl;
    w.y = excl + v.x;
    w.z = excl + v.x + v.y;
    w.w = excl + v.x + v.y + v.z;
    *(uint4*)p = w;
    if (lane == 63) tot[bin] = (int)(excl + s);
}

// Single-block exclusive scan of tot -> tile_base[0..nbins].
__global__ __launch_bounds__(1024) void scanC_kernel(
    const int* __restrict__ tot, int nbins, int* __restrict__ tile_base) {
    __shared__ int part[1024];
    const int t = threadIdx.x;
    const int chunk = (nbins + 1023) >> 10;
    const int lo = min(t * chunk, nbins);
    const int hi = min(lo + chunk, nbins);
    int s = 0;
    for (int i = lo; i < hi; ++i) s += tot[i];
    part[t] = s;
    __syncthreads();
    for (int off = 1; off < 1024; off <<= 1) {
        int add = (t >= off) ? part[t - off] : 0;
        __syncthreads();
        part[t] += add;
        __syncthreads();
    }
    int excl = (t == 0) ? 0 : part[t - 1];
    for (int i = lo; i < hi; ++i) {
        tile_base[i] = excl;
        excl += tot[i];
    }
    if (t == 1023) tile_base[nbins] = part[1023];
}

// Rank replay + scatter into tile-grouped csr.
__global__ __launch_bounds__(256) void fillB_kernel(
    const int* __restrict__ src, const int* __restrict__ dst, int E,
    const unsigned* __restrict__ G, const int* __restrict__ tile_base,
    unsigned* __restrict__ csr, int nbins) {
    __shared__ int rank[2048];
    __shared__ int base[2048];
    const int t = threadIdx.x;
    for (int i = t; i < nbins; i += 256) {
        rank[i] = 0;
        base[i] = tile_base[i] + (int)G[(size_t)i * NBLK + blockIdx.x];
    }
    __syncthreads();
    const int per = (E + NBLK - 1) / NBLK;
    const int lo = blockIdx.x * per;
    const int hi = min(lo + per, E);
    for (int i = lo + t; i < hi; i += 256) {
        const int d = dst[i];
        const int bin = d >> 5;
        const int r = atomicAdd(&rank[bin], 1);
        csr[base[bin] + r] = (unsigned)src[i] | ((unsigned)d << 16);
    }
}

// One block per tile: in-LDS 32-bin counting sort of the tile's csr range
// (row-grouped, in place) + invL_g = 1/max(deg,1). Runs once, reused by both
// sage layers. nE > CAP (never at E/nbins ~512): skip reorder, still correct.
__global__ __launch_bounds__(256) void sortT_kernel(unsigned* __restrict__ csr,
                                                    const int* __restrict__
                                                        tile_base,
                                                    float* __restrict__ invL_g,
                                                    int N) {
    __shared__ unsigned sortedE[CAP];
    __shared__ int rowcnt[32];
    __shared__ int rowofs[32];
    const int b = blockIdx.x;
    const int i0 = b * 32;
    const int t = threadIdx.x;
    const int rs0 = tile_base[b];
    const int re0 = tile_base[b + 1];
    const int nE = re0 - rs0;

    if (t < 32) rowcnt[t] = 0;
    __syncthreads();
    for (int i = t; i < nE; i += 256)
        atomicAdd(&rowcnt[(csr[rs0 + i] >> 16) & 31], 1);
    __syncthreads();
    if (t < 32) {
        const int v = rowcnt[t];
        if (i0 + t < N) invL_g[i0 + t] = 1.0f / fmaxf((float)v, 1.0f);
        int s = v;
#pragma unroll
        for (int off = 1; off < 32; off <<= 1) {
            const int u = __shfl_up(s, off, 32);
            if ((t & 31) >= off) s += u;
        }
        rowofs[t] = s - v;
    }
    __syncthreads();
    if (nE <= CAP) {
        for (int i = t; i < nE; i += 256) {
            const unsigned p = csr[rs0 + i];
            const int k = atomicAdd(&rowofs[(p >> 16) & 31], 1);
            sortedE[k] = p;
        }
        __syncthreads();
        for (int i = t; i < nE; i += 256) csr[rs0 + i] = sortedE[i];
    }
}

// Fused: segmented bf16 gather (fp32 acc into LDS) -> MFMA dual GEMM with
// mean applied at A-frag build. HEAD folds the Linear(128,1).
template <bool HEAD>
__global__ __launch_bounds__(256) void sage_kernel(
    const unsigned short* __restrict__ xb, const unsigned* __restrict__ csr,
    const int* __restrict__ tile_base, const float* __restrict__ invL_g,
    const unsigned short* __restrict__ Bt,  // [128 n][256 k] bf16
    const float* __restrict__ bl, const float* __restrict__ Wout,
    const float* __restrict__ bout, unsigned short* __restrict__ hb_out,
    float* __restrict__ out, int N) {
    __shared__ float aggL[32 * LSTR];
    __shared__ float invL[32];
    __shared__ float redH[64];

    const int b = blockIdx.x;
    const int i0 = b * 32;
    const int t = threadIdx.x;
    const int g = t >> 5;
    const int l = t & 31;
    const int c4 = l << 2;

    for (int i = t; i < 32 * LSTR; i += 256) aggL[i] = 0.f;
    if (t < 32) invL[t] = (i0 + t < N) ? invL_g[i0 + t] : 1.0f;
    __syncthreads();

    // ---- segmented edge-parallel aggregation over row-sorted csr ----
    const int rs0 = tile_base[b];
    const int re0 = tile_base[b + 1];
    const int nE = re0 - rs0;
    int e = rs0 + ((nE * g) >> 3);
    const int ee = rs0 + ((nE * (g + 1)) >> 3);

    float4 acc = make_float4(0.f, 0.f, 0.f, 0.f);
    int cur = (e < ee) ? (int)(csr[e] >> 16) - i0 : -1;

    auto load4 = [&](unsigned p) -> float4 {
        const ushort4 u =
            *(const ushort4*)(xb + (size_t)(p & 0xffffu) * D + c4);
        float4 v;
        v.x = b2f(u.x); v.y = b2f(u.y); v.z = b2f(u.z); v.w = b2f(u.w);
        return v;
    };
    auto step = [&](unsigned p, const float4& v) {
        const int r = (int)(p >> 16) - i0;
        if (r != cur) {
            float* q = aggL + cur * LSTR + c4;
            atomicAdd(q + 0, acc.x);
            atomicAdd(q + 1, acc.y);
            atomicAdd(q + 2, acc.z);
            atomicAdd(q + 3, acc.w);
            acc = make_float4(0.f, 0.f, 0.f, 0.f);
            cur = r;
        }
        acc.x += v.x; acc.y += v.y; acc.z += v.z; acc.w += v.w;
    };

    while (e + 8 <= ee) {
        const unsigned p0 = csr[e + 0], p1 = csr[e + 1];
        const unsigned p2 = csr[e + 2], p3 = csr[e + 3];
        const unsigned p4 = csr[e + 4], p5 = csr[e + 5];
        const unsigned p6 = csr[e + 6], p7 = csr[e + 7];
        const float4 v0 = load4(p0), v1 = load4(p1), v2 = load4(p2),
                     v3 = load4(p3), v4 = load4(p4), v5 = load4(p5),
                     v6 = load4(p6), v7 = load4(p7);
        step(p0, v0); step(p1, v1); step(p2, v2); step(p3, v3);
        step(p4, v4); step(p5, v5); step(p6, v6); step(p7, v7);
        e += 8;
    }
    while (e < ee) {
        const unsigned p = csr[e];
        step(p, load4(p));
        ++e;
    }
    if (cur >= 0) {
        float* q = aggL + cur * LSTR + c4;
        atomicAdd(q + 0, acc.x);
        atomicAdd(q + 1, acc.y);
        atomicAdd(q + 2, acc.z);
        atomicAdd(q + 3, acc.w);
    }
    __syncthreads();

    // ---- MFMA dual GEMM: [agg*inv | x](32x256) @ Bt^T(256x128) ----
    const int wave = t >> 6;
    const int lane = t & 63;
    const int ln = lane & 15;
    const int quad = lane >> 4;
    const int mtile = wave & 1;       // rows mtile*16..+15
    const int nt0 = (wave >> 1) * 4;  // 4 n-tiles per wave
    const int mrow = mtile * 16 + ln;
    const int gmr = i0 + mrow;
    const float inv = invL[mrow];

    f32x4 acc4[4] = {f32x4{0.f, 0.f, 0.f, 0.f}, f32x4{0.f, 0.f, 0.f, 0.f},
                     f32x4{0.f, 0.f, 0.f, 0.f}, f32x4{0.f, 0.f, 0.f, 0.f}};

#pragma unroll
    for (int s = 0; s < 4; ++s) {
        const int kb = s * 32 + quad * 8;
        const float* ap = aggL + mrow * LSTR + kb;
        const float4 fa = *(const float4*)ap;
        const float4 fb = *(const float4*)(ap + 4);
        const short8 aA = {(short)f2bf(fa.x * inv), (short)f2bf(fa.y * inv),
                           (short)f2bf(fa.z * inv), (short)f2bf(fa.w * inv),
                           (short)f2bf(fb.x * inv), (short)f2bf(fb.y * inv),
                           (short)f2bf(fb.z * inv), (short)f2bf(fb.w * inv)};
        short8 aX = {0, 0, 0, 0, 0, 0, 0, 0};
        if (gmr < N) aX = *(const short8*)(xb + (size_t)gmr * D + kb);
#pragma unroll
        for (int nt = 0; nt < 4; ++nt) {
            const int n = (nt0 + nt) * 16 + ln;
            const short8 b1 = *(const short8*)(Bt + n * 256 + kb);
            const short8 b2 = *(const short8*)(Bt + n * 256 + 128 + kb);
            acc4[nt] = __builtin_amdgcn_mfma_f32_16x16x32_bf16(aA, b1, acc4[nt],
                                                               0, 0, 0);
            acc4[nt] = __builtin_amdgcn_mfma_f32_16x16x32_bf16(aX, b2, acc4[nt],
                                                               0, 0, 0);
        }
    }

    // ---- epilogue: C/D layout col=lane&15, row=quad*4+reg ----
    float biasv[4], woutv[4];
#pragma unroll
    for (int nt = 0; nt < 4; ++nt) {
        const int col = (nt0 + nt) * 16 + ln;
        biasv[nt] = bl[col];
        if (HEAD) woutv[nt] = Wout[col];
    }

    if (!HEAD) {
#pragma unroll
        for (int r = 0; r < 4; ++r) {
            const int gr = i0 + mtile * 16 + quad * 4 + r;
            if (gr < N) {
#pragma unroll
                for (int nt = 0; nt < 4; ++nt) {
                    const int col = (nt0 + nt) * 16 + ln;
                    const float v = fmaxf(acc4[nt][r] + biasv[nt], 0.f);
                    hb_out[(size_t)gr * D + col] = f2bf(v);
                }
            }
        }
    } else {
        const float b0 = bout[0];
#pragma unroll
        for (int r = 0; r < 4; ++r) {
            const int row = mtile * 16 + quad * 4 + r;
            float p = 0.f;
#pragma unroll
            for (int nt = 0; nt < 4; ++nt) {
                const float v = fmaxf(acc4[nt][r] + biasv[nt], 0.f);
                p += v * woutv[nt];
            }
            p += __shfl_xor(p, 1);
            p += __shfl_xor(p, 2);
            p += __shfl_xor(p, 4);
            p += __shfl_xor(p, 8);
            if (ln == 0) redH[row * 2 + (wave >> 1)] = p;
        }
        __syncthreads();
        if (t < 32) {
            const int gr = i0 + t;
            if (gr < N) out[gr] = redH[t * 2] + redH[t * 2 + 1] + b0;
        }
    }
}

extern "C" void kernel_launch(void* const* d_in, const int* in_sizes, int n_in,
                              void* d_out, int out_size, void* d_ws,
                              size_t ws_size, hipStream_t stream) {
    const float* x = (const float*)d_in[0];
    const int* ei = (const int*)d_in[1];
    const float* W1l = (const float*)d_in[2];
    const float* b1l = (const float*)d_in[3];
    const float* W1r = (const float*)d_in[4];
    const float* W2l = (const float*)d_in[5];
    const float* b2l = (const float*)d_in[6];
    const float* W2r = (const float*)d_in[7];
    const float* Wout = (const float*)d_in[8];
    const float* bout = (const float*)d_in[9];

    const int N = in_sizes[0] / D;
    const int E = in_sizes[1] / 2;
    const int* src = ei;
    const int* dst = ei + E;

    const int nbins = (N + 31) / 32;  // 32-row tiles (= sage blocks), <= 2048
    const size_t Npad = (size_t)((N + 255) & ~255);
    const size_t Epad = (size_t)((E + 255) & ~255);

    int* tot = (int*)d_ws;                        // [2048]
    int* tile_base = tot + 2048;                  // [2052]
    float* invL_g = (float*)(tile_base + 2052);   // [Npad]
    unsigned* G = (unsigned*)(invL_g + Npad);     // [2048 * NBLK]
    unsigned* csr = G + (size_t)2048 * NBLK;
    unsigned short* xb = (unsigned short*)(csr + Epad);
    unsigned short* hb = xb + (size_t)N * D;
    unsigned short* Bt1 = hb + (size_t)N * D;
    unsigned short* Bt2 = Bt1 + 128 * 256;
    float* out = (float*)d_out;

    const int NX2 = N * D / 2;
    const int prep_blocks = (NX2 + 2 * 32768 + 255) / 256;

    prep_hist_kernel<<<NBLK + prep_blocks, 256, 0, stream>>>(
        x, W1l, W1r, W2l, W2r, (unsigned*)xb, Bt1, Bt2, NX2, dst, E, nbins, G);
    scanB_kernel<<<(nbins + 3) / 4, 256, 0, stream>>>(G, nbins, tot);
    scanC_kernel<<<1, 1024, 0, stream>>>(tot, nbins, tile_base);
    fillB_kernel<<<NBLK, 256, 0, stream>>>(src, dst, E, G, tile_base, csr,
                                           nbins);
    sortT_kernel<<<nbins, 256, 0, stream>>>(csr, tile_base, invL_g, N);

    sage_kernel<false><<<nbins, 256, 0, stream>>>(
        xb, csr, tile_base, invL_g, Bt1, b1l, nullptr, nullptr, hb, nullptr, N);
    sage_kernel<true><<<nbins, 256, 0, stream>>>(
        hb, csr, tile_base, invL_g, Bt2, b2l, Wout, bout, nullptr, out, N);
}